// Round 1
// baseline (495.385 us; speedup 1.0000x reference)
//
#include <hip/hip_runtime.h>
#include <hip/hip_bf16.h>
#include <hip/hip_cooperative_groups.h>

namespace cg = cooperative_groups;

// GCN: 2x GCNConv(128->128) + LeakyReLU(0.1) + mean over channels.
// N=50000, E=1600000, D=128, fp32 in/out.
//
// R10: launch-count attack round 2: 6 -> 3 dispatches.
//   L1: hist + w2m + MFMA gemm (gemm has no deps; overlaps hist instead of
//       serializing behind hist->scan->scatter as in R9b's K4).
//   L2: cooperative build: per-bucket scan -> totals scan -> scatter -> sort,
//       3x grid.sync() (replaces atomic-ticket last-block machinery).
//   L3: cooperative gather+out: persistent grid (occupancy-API sized,
//       __launch_bounds__(256,8) keeps VGPR<=64 -> 8 blocks/CU), gather
//       grid-strided, grid.sync(), scalar out phase.
// Gather inner loop is byte-identical to R9b (56us, latency/VALU mix; R8's
// channel-quartering already shown net-negative).
// Math (verified R2-R8): h[u]=bf16((x@W1)[u]);  g UNSCALED, dinv per-edge fma:
//   mg[u]=dinv[u]*dot(lrelu(dinv[u]*sum_{n in N(u)+u} dinv[n]*h[n] + b1), mean_j W2[:,j]);
//   out[v]=dinv[v]*(mg[v]+sum mg[nbr]) + mean(b2).

#define N_NODES 50000
#define NPAD 50048
#define D 128
#define BK 196           // node buckets: v>>8
#define CHUNK 4096       // edges per stage-1 block
#define WT_STRIDE 136

typedef unsigned int uint;
typedef unsigned short u16;
typedef __attribute__((ext_vector_type(8))) short short8;   // 8 bf16 (4 VGPRs)
typedef __attribute__((ext_vector_type(4))) float floatx4;

__device__ __forceinline__ u16 cvt_bf16(float f) {
    uint u = __float_as_uint(f);
    return (u16)((u + 0x7fffu + ((u >> 16) & 1u)) >> 16);   // RNE
}
__device__ __forceinline__ uint pack_bf2(float a, float b) {
    return (uint)cvt_bf16(a) | ((uint)cvt_bf16(b) << 16);
}

// ---------------- L1: hist chunks + w2m + MFMA gemm ----------------
__global__ __launch_bounds__(256) void hist_w2m_gemm_kernel(
    const int* __restrict__ dst, uint* __restrict__ H,
    const float* __restrict__ W2, const float* __restrict__ b2,
    float* __restrict__ w2m,
    const float* __restrict__ A, const float* __restrict__ W,
    uint* __restrict__ G32, int E, int CHN, int N) {
    __shared__ union {
        uint h[BK];
        u16 wt[128 * WT_STRIDE];           // 34.8 KB
    } sm;
    int t = threadIdx.x, c = blockIdx.x;

    if (c < CHN) {                         // ---- histogram chunk ----
        if (t < BK) sm.h[t] = 0;
        __syncthreads();
        int e0 = c * CHUNK;
        for (int i = t; i < CHUNK; i += 256) {
            int e = e0 + i;
            if (e < E) atomicAdd(&sm.h[dst[e] >> 8], 1u);
        }
        __syncthreads();
        if (t < BK) H[t * CHN + c] = sm.h[t];   // bucket-major for column scan
    } else if (c == CHN) {                 // ---- w2m block ----
        if (t < 128) {
            float s = 0.f;
            for (int j = 0; j < 128; j++) s += W2[t * 128 + j];
            w2m[t] = s * (1.0f / 128.0f);
        } else if (t == 128) {
            float s = 0.f;
            for (int j = 0; j < 128; j++) s += b2[j];
            w2m[128] = s * (1.0f / 128.0f);
        }
    } else {                               // ---- MFMA gemm: g16 = bf16(x@W1), unscaled ----
        int bid = c - CHN - 1;
        for (int i = t; i < 128 * 128; i += 256) {   // stage W1^T as bf16
            int k = i >> 7, n = i & 127;
            sm.wt[n * WT_STRIDE + k] = cvt_bf16(W[i]);
        }
        __syncthreads();

        int wave = t >> 6, lane = t & 63;
        int m = lane & 15, quad = lane >> 4;
        int rowa = bid * 64 + wave * 16 + m;
        int rowc = rowa < N ? rowa : N - 1;
        const float* Arow = A + (long)rowc * D;

        short8 afrag[4];
#pragma unroll
        for (int kt = 0; kt < 4; kt++) {
            int k0 = kt * 32 + quad * 8;
            float4 f0 = *(const float4*)(Arow + k0);
            float4 f1 = *(const float4*)(Arow + k0 + 4);
            short8 af;
            af[0] = (short)cvt_bf16(f0.x); af[1] = (short)cvt_bf16(f0.y);
            af[2] = (short)cvt_bf16(f0.z); af[3] = (short)cvt_bf16(f0.w);
            af[4] = (short)cvt_bf16(f1.x); af[5] = (short)cvt_bf16(f1.y);
            af[6] = (short)cvt_bf16(f1.z); af[7] = (short)cvt_bf16(f1.w);
            afrag[kt] = af;
        }

        int orow0 = bid * 64 + wave * 16;
        for (int n0 = 0; n0 < 128; n0 += 16) {
            floatx4 acc = {0.f, 0.f, 0.f, 0.f};
#pragma unroll
            for (int kt = 0; kt < 4; kt++) {
                short8 bf = *(const short8*)(sm.wt + (n0 + m) * WT_STRIDE + kt * 32 + quad * 8);
                acc = __builtin_amdgcn_mfma_f32_16x16x32_bf16(afrag[kt], bf, acc, 0, 0, 0);
            }
#pragma unroll
            for (int r = 0; r < 4; r++) {
                float val = acc[r];
                float oth = __shfl_xor(val, 1, 64);      // partner column
                int orow = orow0 + quad * 4 + r;
                if (orow < N && (m & 1) == 0)
                    G32[(long)orow * 64 + ((n0 + m) >> 1)] = pack_bf2(val, oth);
            }
        }
    }
}

// ---------------- L2: cooperative build: scan -> totals -> scatter -> sort ----------------
__global__ __launch_bounds__(256) void build_kernel(
    const int* __restrict__ src, const int* __restrict__ dst,
    uint* __restrict__ H, uint* __restrict__ T, uint* __restrict__ B,
    int* __restrict__ row, float* __restrict__ dinv, u16* __restrict__ esrc,
    uint* __restrict__ EB, int E, int N, int CHN) {
    cg::grid_group grid = cg::this_grid();
    __shared__ union {
        uint s[256];
        struct { uint cnt[256]; uint s2[256]; uint cur2[256]; } srt;
        uint cur[BK];
    } sm;
    int t = threadIdx.x, b = blockIdx.x;

    // Phase A: per-bucket exclusive scan of H[b][*] over chunks
    if (b < BK) {
        uint carry = 0;
        for (int base = 0; base < CHN; base += 256) {
            int idx = base + t;
            uint v = (idx < CHN) ? H[b * CHN + idx] : 0u;
            sm.s[t] = v;
            __syncthreads();
#pragma unroll
            for (int off = 1; off < 256; off <<= 1) {
                uint u = (t >= off) ? sm.s[t - off] : 0u;
                __syncthreads();
                sm.s[t] += u;
                __syncthreads();
            }
            if (idx < CHN) H[b * CHN + idx] = carry + sm.s[t] - v;   // exclusive + carry
            carry += sm.s[255];
            __syncthreads();
        }
        if (t == 0) atomicExch(&T[b], carry);   // device-scope (crosses XCD L2s)
    }
    grid.sync();

    // Phase B: block 0 scans bucket totals -> B[] (exclusive bucket offsets)
    if (b == 0) {
        uint v = (t < BK) ? atomicAdd(&T[t], 0u) : 0u;
        sm.s[t] = v;
        __syncthreads();
#pragma unroll
        for (int off = 1; off < 256; off <<= 1) {
            uint u = (t >= off) ? sm.s[t - off] : 0u;
            __syncthreads();
            sm.s[t] += u;
            __syncthreads();
        }
        if (t < BK) B[t] = sm.s[t] - v;
        if (t == 0) { B[BK] = (uint)E; row[N] = E; }
    }
    grid.sync();

    // Phase C: scatter chunk b into bucket regions (LDS cursors)
    if (b < CHN) {
        if (t < BK) sm.cur[t] = B[t] + H[t * CHN + b];
        __syncthreads();
        int e0 = b * CHUNK;
        for (int i = t; i < CHUNK; i += 256) {
            int e = e0 + i;
            if (e < E) {
                int d = dst[e];
                uint slot = atomicAdd(&sm.cur[d >> 8], 1u);
                EB[slot] = ((uint)(d & 255) << 16) | (uint)src[e];
            }
        }
    }
    grid.sync();

    // Phase D: per-bucket counting sort by dst&255 -> esrc, row, dinv
    if (b < BK) {
        uint base = B[b], ne = B[b + 1] - base;
        sm.srt.cnt[t] = 0;
        __syncthreads();
        for (uint i = t; i < ne; i += 256) atomicAdd(&sm.srt.cnt[EB[base + i] >> 16], 1u);
        __syncthreads();
        uint cval = sm.srt.cnt[t];
        sm.srt.s2[t] = cval;
        __syncthreads();
#pragma unroll
        for (int off = 1; off < 256; off <<= 1) {
            uint u = (t >= off) ? sm.srt.s2[t - off] : 0u;
            __syncthreads();
            sm.srt.s2[t] += u;
            __syncthreads();
        }
        uint p = sm.srt.s2[t] - cval;       // exclusive prefix within bucket
        int v = (b << 8) + t;
        if (v < N) {
            row[v] = (int)(base + p);
            dinv[v] = rsqrtf((float)(cval + 1u));   // +1 self-loop
        }
        sm.srt.cur2[t] = base + p;
        __syncthreads();
        for (uint i = t; i < ne; i += 256) {
            uint u = EB[base + i];
            uint slot = atomicAdd(&sm.srt.cur2[u >> 16], 1u);
            esrc[slot] = (u16)(u & 0xffffu);
        }
    }
}

// ---------------- L3: cooperative gather (persistent) -> grid.sync -> out ----------------
// Gather: R7 structure, byte-identical inner loop: one wave/node; 8 chains x 8
// lanes; 2 uint4/edge, 2-deep pipeline; dinv[src] per edge via fma.
__global__ __launch_bounds__(256, 8) void gather_out_kernel(
    const int* __restrict__ row, const u16* __restrict__ esrc,
    const uint* __restrict__ g16, const float* __restrict__ dinv,
    const float* __restrict__ b1, const float* __restrict__ w2m,
    float* __restrict__ mg, float* __restrict__ out, int N) {
    cg::grid_group grid = cg::this_grid();
    int wave = threadIdx.x >> 6;
    int lane = threadIdx.x & 63;
    int sub = lane & 7;        // 16-channel slice: uint4 pair 2*sub, 2*sub+1
    int nb = lane >> 3;        // 8 neighbor chains
    const uint4* gv = (const uint4*)g16;   // 16 uint4 per 256B row

#define ACC8(ua, ub, wgt) {                                              \
    uint uu[8] = {(ua).x, (ua).y, (ua).z, (ua).w, (ub).x, (ub).y, (ub).z, (ub).w}; \
    _Pragma("unroll")                                                    \
    for (int i = 0; i < 8; i++) {                                        \
        acc[2*i]   += (wgt) * __uint_as_float(uu[i] << 16);              \
        acc[2*i+1] += (wgt) * __uint_as_float(uu[i] & 0xffff0000u);      \
    } }

    for (int v0 = blockIdx.x * 4; v0 < N; v0 += gridDim.x * 4) {
        int v = v0 + wave;
        if (v < N) {
            float dvv = dinv[v];
            float acc[16];
#pragma unroll
            for (int i = 0; i < 16; i++) acc[i] = 0.f;

            if (nb == 0) {             // self-loop term: dinv[v]*h[v]
                long rb = (long)v * 16 + 2 * sub;
                uint4 ua = gv[rb], ub = gv[rb + 1];
                ACC8(ua, ub, dvv)
            }
            int jb = row[v], je = row[v + 1];
            int j = jb + nb;
            if (j < je) {              // 2-deep pipeline per chain
                int s0 = esrc[j];
                float wA = dinv[s0];
                long r0 = (long)s0 * 16 + 2 * sub;
                uint4 p0 = gv[r0], p1 = gv[r0 + 1];
                j += 8;
                while (j < je) {
                    int s1 = esrc[j];
                    float wB = dinv[s1];
                    long r1 = (long)s1 * 16 + 2 * sub;
                    uint4 q0 = gv[r1], q1 = gv[r1 + 1];
                    j += 8;
                    ACC8(p0, p1, wA)
                    p0 = q0; p1 = q1; wA = wB;
                }
                ACC8(p0, p1, wA)
            }

            // reduce the 8 chains
#pragma unroll
            for (int i = 0; i < 16; i++) {
                acc[i] += __shfl_xor(acc[i], 8, 64);
                acc[i] += __shfl_xor(acc[i], 16, 64);
                acc[i] += __shfl_xor(acc[i], 32, 64);
            }

            if (nb == 0) {             // lane sub holds channels 16*sub .. 16*sub+15
                const float4* bp = (const float4*)b1;
                const float4* wp = (const float4*)w2m;
                float s = 0.f;
#pragma unroll
                for (int q4 = 0; q4 < 4; q4++) {
                    float4 bb = bp[sub * 4 + q4];
                    float4 wm = wp[sub * 4 + q4];
                    float t0 = dvv * acc[4*q4 + 0] + bb.x; t0 = t0 >= 0.f ? t0 : 0.1f * t0;
                    float t1 = dvv * acc[4*q4 + 1] + bb.y; t1 = t1 >= 0.f ? t1 : 0.1f * t1;
                    float t2 = dvv * acc[4*q4 + 2] + bb.z; t2 = t2 >= 0.f ? t2 : 0.1f * t2;
                    float t3 = dvv * acc[4*q4 + 3] + bb.w; t3 = t3 >= 0.f ? t3 : 0.1f * t3;
                    s += t0 * wm.x + t1 * wm.y + t2 * wm.z + t3 * wm.w;
                }
                s += __shfl_xor(s, 1, 64);
                s += __shfl_xor(s, 2, 64);
                s += __shfl_xor(s, 4, 64);
                if (sub == 0) mg[v] = dvv * s;
            }
        }
    }
#undef ACC8

    grid.sync();

    // out phase: scalar aggregate for conv2 + mean
    float w2c = w2m[128];
    for (int v = blockIdx.x * 256 + threadIdx.x; v < N; v += gridDim.x * 256) {
        float acc = mg[v];
        int jb = row[v], je = row[v + 1];
        int j = jb;
        for (; j + 8 <= je; j += 8) {
            acc += mg[esrc[j]] + mg[esrc[j + 1]] + mg[esrc[j + 2]] + mg[esrc[j + 3]] +
                   mg[esrc[j + 4]] + mg[esrc[j + 5]] + mg[esrc[j + 6]] + mg[esrc[j + 7]];
        }
        for (; j < je; j++) acc += mg[esrc[j]];
        out[v] = dinv[v] * acc + w2c;
    }
}

extern "C" void kernel_launch(void* const* d_in, const int* in_sizes, int n_in,
                              void* d_out, int out_size, void* d_ws, size_t ws_size,
                              hipStream_t stream) {
    const float* x  = (const float*)d_in[0];
    const int* ei   = (const int*)d_in[1];
    const float* W1 = (const float*)d_in[2];
    const float* b1 = (const float*)d_in[3];
    const float* W2 = (const float*)d_in[4];
    const float* b2 = (const float*)d_in[5];
    float* out = (float*)d_out;

    int N = N_NODES;
    int E = in_sizes[1] / 2;
    const int* src = ei;
    const int* dst = ei + E;
    int CHN = (E + CHUNK - 1) / CHUNK;   // 391
    int GB  = (N + 63) / 64;             // 782

    // workspace (4B units). Layout identical to R9b (counter slot kept, unused).
    float*    dinv    = (float*)d_ws;                     // [NPAD]
    int*      row     = (int*)(dinv + NPAD);              // [NPAD+16]
    uint*     B       = (uint*)(row + NPAD + 16);         // [256] (BK+1 used)
    float*    w2m     = (float*)(B + 256);                // [256] ([128]=mean b2)
    float*    mg      = w2m + 256;                        // [NPAD]
    uint*     T       = (uint*)(mg + NPAD);               // [256]
    uint*     counter = T + 256;                          // [16] (unused, layout kept)
    uint*     g16u    = counter + 16;                     // [NPAD*64] (16B aligned)
    u16*      esrc    = (u16*)(g16u + (long)NPAD * 64);   // [E] u16
    uint*     H       = (uint*)(esrc + E);                // [BK*CHN]
    uint*     EB      = H + BK * CHN;                     // [E]
    (void)counter;

    // L1: hist chunks + w2m + MFMA gemm (gemm dep-free; overlaps hist)
    hist_w2m_gemm_kernel<<<CHN + 1 + GB, 256, 0, stream>>>(dst, H, W2, b2, w2m,
                                                           x, W1, g16u, E, CHN, N);

    // L2: cooperative scan -> totals -> scatter -> sort (391 blocks co-resident)
    {
        int grid2 = (CHN > BK) ? CHN : BK;
        void* args[] = {(void*)&src, (void*)&dst, (void*)&H, (void*)&T, (void*)&B,
                        (void*)&row, (void*)&dinv, (void*)&esrc, (void*)&EB,
                        (void*)&E, (void*)&N, (void*)&CHN};
        hipLaunchCooperativeKernel((const void*)build_kernel, dim3(grid2), dim3(256),
                                   args, 0, stream);
    }

    // L3: cooperative persistent gather -> grid.sync -> out
    {
        static int maxb = -1;
        if (maxb < 0) {
            int mb = 0;
            if (hipOccupancyMaxActiveBlocksPerMultiprocessor(
                    &mb, (const void*)gather_out_kernel, 256, 0) != hipSuccess || mb < 1)
                mb = 4;
            maxb = mb;
        }
        int grid3 = maxb * 256;              // 256 CUs
        int ng = (N + 3) / 4;                // 12500 node-groups
        if (grid3 > ng) grid3 = ng;
        if (grid3 > 2048) grid3 = 2048;
        void* args[] = {(void*)&row, (void*)&esrc, (void*)&g16u, (void*)&dinv,
                        (void*)&b1, (void*)&w2m, (void*)&mg, (void*)&out, (void*)&N};
        hipLaunchCooperativeKernel((const void*)gather_out_kernel, dim3(grid3), dim3(256),
                                   args, 0, stream);
    }
}

// Round 2
// 347.010 us; speedup vs baseline: 1.4276x; 1.4276x over previous
//
#include <hip/hip_runtime.h>
#include <hip/hip_bf16.h>
#include <hip/hip_cooperative_groups.h>

namespace cg = cooperative_groups;

// GCN: 2x GCNConv(128->128) + LeakyReLU(0.1) + mean over channels.
// N=50000, E=1600000, D=128, fp32 in/out.
//
// R11: half-revert of R10. R10's persistent cooperative gather spilled
//   (VGPR 36->32, WRITE_SIZE +4.7MB scratch, 56->325us). Keep the two safe
//   fusions, restore gather/out byte-identical to R9b (196us baseline):
//   L1: hist + w2m + MFMA gemm (gemm dep-free, overlaps hist).
//   L2: cooperative build: scan -> totals -> scatter -> sort (3x grid.sync).
//   L3: gather_node_kernel, R9b verbatim (12500 blocks, 4 nodes/block).
//   L4: out_kernel, R9b verbatim.
// Math (verified R2-R8): h[u]=bf16((x@W1)[u]);  g UNSCALED, dinv per-edge fma:
//   mg[u]=dinv[u]*dot(lrelu(dinv[u]*sum_{n in N(u)+u} dinv[n]*h[n] + b1), mean_j W2[:,j]);
//   out[v]=dinv[v]*(mg[v]+sum mg[nbr]) + mean(b2).

#define N_NODES 50000
#define NPAD 50048
#define D 128
#define BK 196           // node buckets: v>>8
#define CHUNK 4096       // edges per stage-1 block
#define WT_STRIDE 136

typedef unsigned int uint;
typedef unsigned short u16;
typedef __attribute__((ext_vector_type(8))) short short8;   // 8 bf16 (4 VGPRs)
typedef __attribute__((ext_vector_type(4))) float floatx4;

__device__ __forceinline__ u16 cvt_bf16(float f) {
    uint u = __float_as_uint(f);
    return (u16)((u + 0x7fffu + ((u >> 16) & 1u)) >> 16);   // RNE
}
__device__ __forceinline__ uint pack_bf2(float a, float b) {
    return (uint)cvt_bf16(a) | ((uint)cvt_bf16(b) << 16);
}

// ---------------- L1: hist chunks + w2m + MFMA gemm ----------------
__global__ __launch_bounds__(256) void hist_w2m_gemm_kernel(
    const int* __restrict__ dst, uint* __restrict__ H,
    const float* __restrict__ W2, const float* __restrict__ b2,
    float* __restrict__ w2m,
    const float* __restrict__ A, const float* __restrict__ W,
    uint* __restrict__ G32, int E, int CHN, int N) {
    __shared__ union {
        uint h[BK];
        u16 wt[128 * WT_STRIDE];           // 34.8 KB
    } sm;
    int t = threadIdx.x, c = blockIdx.x;

    if (c < CHN) {                         // ---- histogram chunk ----
        if (t < BK) sm.h[t] = 0;
        __syncthreads();
        int e0 = c * CHUNK;
        for (int i = t; i < CHUNK; i += 256) {
            int e = e0 + i;
            if (e < E) atomicAdd(&sm.h[dst[e] >> 8], 1u);
        }
        __syncthreads();
        if (t < BK) H[t * CHN + c] = sm.h[t];   // bucket-major for column scan
    } else if (c == CHN) {                 // ---- w2m block ----
        if (t < 128) {
            float s = 0.f;
            for (int j = 0; j < 128; j++) s += W2[t * 128 + j];
            w2m[t] = s * (1.0f / 128.0f);
        } else if (t == 128) {
            float s = 0.f;
            for (int j = 0; j < 128; j++) s += b2[j];
            w2m[128] = s * (1.0f / 128.0f);
        }
    } else {                               // ---- MFMA gemm: g16 = bf16(x@W1), unscaled ----
        int bid = c - CHN - 1;
        for (int i = t; i < 128 * 128; i += 256) {   // stage W1^T as bf16
            int k = i >> 7, n = i & 127;
            sm.wt[n * WT_STRIDE + k] = cvt_bf16(W[i]);
        }
        __syncthreads();

        int wave = t >> 6, lane = t & 63;
        int m = lane & 15, quad = lane >> 4;
        int rowa = bid * 64 + wave * 16 + m;
        int rowc = rowa < N ? rowa : N - 1;
        const float* Arow = A + (long)rowc * D;

        short8 afrag[4];
#pragma unroll
        for (int kt = 0; kt < 4; kt++) {
            int k0 = kt * 32 + quad * 8;
            float4 f0 = *(const float4*)(Arow + k0);
            float4 f1 = *(const float4*)(Arow + k0 + 4);
            short8 af;
            af[0] = (short)cvt_bf16(f0.x); af[1] = (short)cvt_bf16(f0.y);
            af[2] = (short)cvt_bf16(f0.z); af[3] = (short)cvt_bf16(f0.w);
            af[4] = (short)cvt_bf16(f1.x); af[5] = (short)cvt_bf16(f1.y);
            af[6] = (short)cvt_bf16(f1.z); af[7] = (short)cvt_bf16(f1.w);
            afrag[kt] = af;
        }

        int orow0 = bid * 64 + wave * 16;
        for (int n0 = 0; n0 < 128; n0 += 16) {
            floatx4 acc = {0.f, 0.f, 0.f, 0.f};
#pragma unroll
            for (int kt = 0; kt < 4; kt++) {
                short8 bf = *(const short8*)(sm.wt + (n0 + m) * WT_STRIDE + kt * 32 + quad * 8);
                acc = __builtin_amdgcn_mfma_f32_16x16x32_bf16(afrag[kt], bf, acc, 0, 0, 0);
            }
#pragma unroll
            for (int r = 0; r < 4; r++) {
                float val = acc[r];
                float oth = __shfl_xor(val, 1, 64);      // partner column
                int orow = orow0 + quad * 4 + r;
                if (orow < N && (m & 1) == 0)
                    G32[(long)orow * 64 + ((n0 + m) >> 1)] = pack_bf2(val, oth);
            }
        }
    }
}

// ---------------- L2: cooperative build: scan -> totals -> scatter -> sort ----------------
__global__ __launch_bounds__(256) void build_kernel(
    const int* __restrict__ src, const int* __restrict__ dst,
    uint* __restrict__ H, uint* __restrict__ T, uint* __restrict__ B,
    int* __restrict__ row, float* __restrict__ dinv, u16* __restrict__ esrc,
    uint* __restrict__ EB, int E, int N, int CHN) {
    cg::grid_group grid = cg::this_grid();
    __shared__ union {
        uint s[256];
        struct { uint cnt[256]; uint s2[256]; uint cur2[256]; } srt;
        uint cur[BK];
    } sm;
    int t = threadIdx.x, b = blockIdx.x;

    // Phase A: per-bucket exclusive scan of H[b][*] over chunks
    if (b < BK) {
        uint carry = 0;
        for (int base = 0; base < CHN; base += 256) {
            int idx = base + t;
            uint v = (idx < CHN) ? H[b * CHN + idx] : 0u;
            sm.s[t] = v;
            __syncthreads();
#pragma unroll
            for (int off = 1; off < 256; off <<= 1) {
                uint u = (t >= off) ? sm.s[t - off] : 0u;
                __syncthreads();
                sm.s[t] += u;
                __syncthreads();
            }
            if (idx < CHN) H[b * CHN + idx] = carry + sm.s[t] - v;   // exclusive + carry
            carry += sm.s[255];
            __syncthreads();
        }
        if (t == 0) atomicExch(&T[b], carry);   // device-scope (crosses XCD L2s)
    }
    grid.sync();

    // Phase B: block 0 scans bucket totals -> B[] (exclusive bucket offsets)
    if (b == 0) {
        uint v = (t < BK) ? atomicAdd(&T[t], 0u) : 0u;
        sm.s[t] = v;
        __syncthreads();
#pragma unroll
        for (int off = 1; off < 256; off <<= 1) {
            uint u = (t >= off) ? sm.s[t - off] : 0u;
            __syncthreads();
            sm.s[t] += u;
            __syncthreads();
        }
        if (t < BK) B[t] = sm.s[t] - v;
        if (t == 0) { B[BK] = (uint)E; row[N] = E; }
    }
    grid.sync();

    // Phase C: scatter chunk b into bucket regions (LDS cursors)
    if (b < CHN) {
        if (t < BK) sm.cur[t] = B[t] + H[t * CHN + b];
        __syncthreads();
        int e0 = b * CHUNK;
        for (int i = t; i < CHUNK; i += 256) {
            int e = e0 + i;
            if (e < E) {
                int d = dst[e];
                uint slot = atomicAdd(&sm.cur[d >> 8], 1u);
                EB[slot] = ((uint)(d & 255) << 16) | (uint)src[e];
            }
        }
    }
    grid.sync();

    // Phase D: per-bucket counting sort by dst&255 -> esrc, row, dinv
    if (b < BK) {
        uint base = B[b], ne = B[b + 1] - base;
        sm.srt.cnt[t] = 0;
        __syncthreads();
        for (uint i = t; i < ne; i += 256) atomicAdd(&sm.srt.cnt[EB[base + i] >> 16], 1u);
        __syncthreads();
        uint cval = sm.srt.cnt[t];
        sm.srt.s2[t] = cval;
        __syncthreads();
#pragma unroll
        for (int off = 1; off < 256; off <<= 1) {
            uint u = (t >= off) ? sm.srt.s2[t - off] : 0u;
            __syncthreads();
            sm.srt.s2[t] += u;
            __syncthreads();
        }
        uint p = sm.srt.s2[t] - cval;       // exclusive prefix within bucket
        int v = (b << 8) + t;
        if (v < N) {
            row[v] = (int)(base + p);
            dinv[v] = rsqrtf((float)(cval + 1u));   // +1 self-loop
        }
        sm.srt.cur2[t] = base + p;
        __syncthreads();
        for (uint i = t; i < ne; i += 256) {
            uint u = EB[base + i];
            uint slot = atomicAdd(&sm.srt.cur2[u >> 16], 1u);
            esrc[slot] = (u16)(u & 0xffffu);
        }
    }
}

// ---------------- L3: fused gather(bf16, dinv-fma) + leakyrelu + dot(w2m) ----------------
// R9b verbatim: one wave/node; 8 chains x 8 lanes; 2 uint4/edge, 2-deep pipeline.
// dinv[src] applied per edge via fma (g is unscaled).
__global__ __launch_bounds__(256) void gather_node_kernel(
    const int* __restrict__ row, const u16* __restrict__ esrc,
    const uint* __restrict__ g16, const float* __restrict__ dinv,
    const float* __restrict__ b1, const float* __restrict__ w2m,
    float* __restrict__ mg, int N) {
    int wave = threadIdx.x >> 6;
    int lane = threadIdx.x & 63;
    int sub = lane & 7;        // 16-channel slice: uint4 pair 2*sub, 2*sub+1
    int nb = lane >> 3;        // 8 neighbor chains
    int v = blockIdx.x * 4 + wave;
    if (v >= N) return;

    const uint4* gv = (const uint4*)g16;   // 16 uint4 per 256B row
    float dvv = dinv[v];
    float acc[16];
#pragma unroll
    for (int i = 0; i < 16; i++) acc[i] = 0.f;

#define ACC8(ua, ub, wgt) {                                              \
    uint uu[8] = {(ua).x, (ua).y, (ua).z, (ua).w, (ub).x, (ub).y, (ub).z, (ub).w}; \
    _Pragma("unroll")                                                    \
    for (int i = 0; i < 8; i++) {                                        \
        acc[2*i]   += (wgt) * __uint_as_float(uu[i] << 16);              \
        acc[2*i+1] += (wgt) * __uint_as_float(uu[i] & 0xffff0000u);      \
    } }

    if (nb == 0) {             // self-loop term: dinv[v]*h[v]
        long rb = (long)v * 16 + 2 * sub;
        uint4 ua = gv[rb], ub = gv[rb + 1];
        ACC8(ua, ub, dvv)
    }
    int jb = row[v], je = row[v + 1];
    int j = jb + nb;
    if (j < je) {              // 2-deep pipeline per chain
        int s0 = esrc[j];
        float wA = dinv[s0];
        long r0 = (long)s0 * 16 + 2 * sub;
        uint4 p0 = gv[r0], p1 = gv[r0 + 1];
        j += 8;
        while (j < je) {
            int s1 = esrc[j];
            float wB = dinv[s1];
            long r1 = (long)s1 * 16 + 2 * sub;
            uint4 q0 = gv[r1], q1 = gv[r1 + 1];
            j += 8;
            ACC8(p0, p1, wA)
            p0 = q0; p1 = q1; wA = wB;
        }
        ACC8(p0, p1, wA)
    }
#undef ACC8

    // reduce the 8 chains
#pragma unroll
    for (int i = 0; i < 16; i++) {
        acc[i] += __shfl_xor(acc[i], 8, 64);
        acc[i] += __shfl_xor(acc[i], 16, 64);
        acc[i] += __shfl_xor(acc[i], 32, 64);
    }

    if (nb == 0) {             // lane sub holds channels 16*sub .. 16*sub+15
        const float4* bp = (const float4*)b1;
        const float4* wp = (const float4*)w2m;
        float s = 0.f;
#pragma unroll
        for (int q4 = 0; q4 < 4; q4++) {
            float4 bb = bp[sub * 4 + q4];
            float4 wm = wp[sub * 4 + q4];
            float t0 = dvv * acc[4*q4 + 0] + bb.x; t0 = t0 >= 0.f ? t0 : 0.1f * t0;
            float t1 = dvv * acc[4*q4 + 1] + bb.y; t1 = t1 >= 0.f ? t1 : 0.1f * t1;
            float t2 = dvv * acc[4*q4 + 2] + bb.z; t2 = t2 >= 0.f ? t2 : 0.1f * t2;
            float t3 = dvv * acc[4*q4 + 3] + bb.w; t3 = t3 >= 0.f ? t3 : 0.1f * t3;
            s += t0 * wm.x + t1 * wm.y + t2 * wm.z + t3 * wm.w;
        }
        s += __shfl_xor(s, 1, 64);
        s += __shfl_xor(s, 2, 64);
        s += __shfl_xor(s, 4, 64);
        if (sub == 0) mg[v] = dvv * s;
    }
}

// ---------------- L4: scalar aggregate for conv2 + mean ----------------
__global__ void out_kernel(const int* __restrict__ row, const u16* __restrict__ esrc,
                           const float* __restrict__ mg, const float* __restrict__ dinv,
                           const float* __restrict__ w2m, float* __restrict__ out, int N) {
    int v = blockIdx.x * blockDim.x + threadIdx.x;
    if (v >= N) return;
    float acc = mg[v];
    int jb = row[v], je = row[v + 1];
    int j = jb;
    for (; j + 8 <= je; j += 8) {
        acc += mg[esrc[j]] + mg[esrc[j + 1]] + mg[esrc[j + 2]] + mg[esrc[j + 3]] +
               mg[esrc[j + 4]] + mg[esrc[j + 5]] + mg[esrc[j + 6]] + mg[esrc[j + 7]];
    }
    for (; j < je; j++) acc += mg[esrc[j]];
    out[v] = dinv[v] * acc + w2m[128];
}

extern "C" void kernel_launch(void* const* d_in, const int* in_sizes, int n_in,
                              void* d_out, int out_size, void* d_ws, size_t ws_size,
                              hipStream_t stream) {
    const float* x  = (const float*)d_in[0];
    const int* ei   = (const int*)d_in[1];
    const float* W1 = (const float*)d_in[2];
    const float* b1 = (const float*)d_in[3];
    const float* W2 = (const float*)d_in[4];
    const float* b2 = (const float*)d_in[5];
    float* out = (float*)d_out;

    int N = N_NODES;
    int E = in_sizes[1] / 2;
    const int* src = ei;
    const int* dst = ei + E;
    int CHN = (E + CHUNK - 1) / CHUNK;   // 391
    int GB  = (N + 63) / 64;             // 782
    int nblocks = (N + 255) / 256;       // 196

    // workspace (4B units). Layout identical to R9b.
    float*    dinv    = (float*)d_ws;                     // [NPAD]
    int*      row     = (int*)(dinv + NPAD);              // [NPAD+16]
    uint*     B       = (uint*)(row + NPAD + 16);         // [256] (BK+1 used)
    float*    w2m     = (float*)(B + 256);                // [256] ([128]=mean b2)
    float*    mg      = w2m + 256;                        // [NPAD]
    uint*     T       = (uint*)(mg + NPAD);               // [256]
    uint*     counter = T + 256;                          // [16] (unused, layout kept)
    uint*     g16u    = counter + 16;                     // [NPAD*64] (16B aligned)
    u16*      esrc    = (u16*)(g16u + (long)NPAD * 64);   // [E] u16
    uint*     H       = (uint*)(esrc + E);                // [BK*CHN]
    uint*     EB      = H + BK * CHN;                     // [E]
    (void)counter;

    // L1: hist chunks + w2m + MFMA gemm (gemm dep-free; overlaps hist)
    hist_w2m_gemm_kernel<<<CHN + 1 + GB, 256, 0, stream>>>(dst, H, W2, b2, w2m,
                                                           x, W1, g16u, E, CHN, N);

    // L2: cooperative scan -> totals -> scatter -> sort (391 blocks co-resident)
    {
        int grid2 = (CHN > BK) ? CHN : BK;
        void* args[] = {(void*)&src, (void*)&dst, (void*)&H, (void*)&T, (void*)&B,
                        (void*)&row, (void*)&dinv, (void*)&esrc, (void*)&EB,
                        (void*)&E, (void*)&N, (void*)&CHN};
        hipLaunchCooperativeKernel((const void*)build_kernel, dim3(grid2), dim3(256),
                                   args, 0, stream);
    }

    // L3: gather + lrelu + dot -> mg (R9b verbatim)
    gather_node_kernel<<<(N + 3) / 4, 256, 0, stream>>>(row, esrc, g16u, dinv, b1, w2m, mg, N);
    // L4: scalar aggregate + mean -> out (R9b verbatim)
    out_kernel<<<nblocks, 256, 0, stream>>>(row, esrc, mg, dinv, w2m, out, N);
}

// Round 3
// 206.749 us; speedup vs baseline: 2.3961x; 1.6784x over previous
//
#include <hip/hip_runtime.h>
#include <hip/hip_bf16.h>

// GCN: 2x GCNConv(128->128) + LeakyReLU(0.1) + mean over channels.
// N=50000, E=1600000, D=128, fp32 in/out.
//
// R12: full revert to R9b 6-kernel structure (197.8us known-good).
//   R10/R11 lesson: cg grid.sync() ~45us each on 8-XCD MI355X (build_kernel
//   167us at 0.7% VALU); cooperative fusion strictly worse than ~6us kernel
//   boundaries. Atomic-ticket (K2) stays the only cheap cross-block sync.
// Single change vs R9b: gather inner loop 2-deep pipeline -> 4-edge flat
//   batch per chain (all 12 loads issued before ACCs; tail via clamp+w=0,
//   exact since 0*finite=0). Avg deg 32 / 8 chains = 4 edges/chain -> one
//   batch covers the typical node; 4x memory-level parallelism.
//   32-bit gv indices (table 12.8MB) to hold VGPR <= 64 (8 blocks/CU).
// Math (verified R2-R8): h[u]=bf16((x@W1)[u]);  g UNSCALED, dinv per-edge fma:
//   mg[u]=dinv[u]*dot(lrelu(dinv[u]*sum_{n in N(u)+u} dinv[n]*h[n] + b1), mean_j W2[:,j]);
//   out[v]=dinv[v]*(mg[v]+sum mg[nbr]) + mean(b2).

#define N_NODES 50000
#define NPAD 50048
#define D 128
#define BK 196           // node buckets: v>>8
#define CHUNK 4096       // edges per stage-1 block

typedef unsigned int uint;
typedef unsigned short u16;
typedef __attribute__((ext_vector_type(8))) short short8;   // 8 bf16 (4 VGPRs)
typedef __attribute__((ext_vector_type(4))) float floatx4;

__device__ __forceinline__ u16 cvt_bf16(float f) {
    uint u = __float_as_uint(f);
    return (u16)((u + 0x7fffu + ((u >> 16) & 1u)) >> 16);   // RNE
}
__device__ __forceinline__ uint pack_bf2(float a, float b) {
    return (uint)cvt_bf16(a) | ((uint)cvt_bf16(b) << 16);
}

// ---------------- K1: per-chunk bucket histogram  +  w2m  +  counter init ----------------
__global__ void hist_w2m_kernel(const int* __restrict__ dst, uint* __restrict__ H,
                                const float* __restrict__ W2, const float* __restrict__ b2,
                                float* __restrict__ w2m, uint* __restrict__ counter,
                                int E, int CHN) {
    int t = threadIdx.x, c = blockIdx.x;
    if (c < CHN) {                         // histogram chunk
        __shared__ uint h[BK];
        if (t < BK) h[t] = 0;
        __syncthreads();
        int e0 = c * CHUNK;
        for (int i = t; i < CHUNK; i += 256) {
            int e = e0 + i;
            if (e < E) atomicAdd(&h[dst[e] >> 8], 1u);
        }
        __syncthreads();
        if (t < BK) H[t * CHN + c] = h[t]; // bucket-major for column scan
    } else {                               // w2m block
        if (t < 128) {
            float s = 0.f;
            for (int j = 0; j < 128; j++) s += W2[t * 128 + j];
            w2m[t] = s * (1.0f / 128.0f);
        } else if (t == 128) {
            float s = 0.f;
            for (int j = 0; j < 128; j++) s += b2[j];
            w2m[128] = s * (1.0f / 128.0f);
        } else if (t == 129) {
            *counter = 0;                  // for K2 last-block detection
        }
    }
}

// ---------------- K2: per-bucket scan over chunks; last block scans totals ----------------
__global__ void scan_kernel(uint* __restrict__ H, uint* __restrict__ T, uint* __restrict__ B,
                            int* __restrict__ row, uint* __restrict__ counter,
                            int CHN, int E, int N) {
    __shared__ uint s[256];
    __shared__ uint ticket_sh;
    int t = threadIdx.x, b = blockIdx.x;
    uint carry = 0;
    for (int base = 0; base < CHN; base += 256) {
        int idx = base + t;
        uint v = (idx < CHN) ? H[b * CHN + idx] : 0u;
        s[t] = v;
        __syncthreads();
#pragma unroll
        for (int off = 1; off < 256; off <<= 1) {
            uint u = (t >= off) ? s[t - off] : 0u;
            __syncthreads();
            s[t] += u;
            __syncthreads();
        }
        if (idx < CHN) H[b * CHN + idx] = carry + s[t] - v;   // exclusive + carry
        carry += s[255];
        __syncthreads();
    }
    if (t == 0) {
        atomicExch(&T[b], carry);          // device-scope store (crosses XCD L2s)
        __threadfence();
        ticket_sh = atomicAdd(counter, 1);
    }
    __syncthreads();
    if (ticket_sh == (uint)(gridDim.x - 1)) {      // last block: scan bucket totals
        __threadfence();
        uint v = (t < BK) ? atomicAdd(&T[t], 0u) : 0u;   // atomic read (coherent)
        s[t] = v;
        __syncthreads();
#pragma unroll
        for (int off = 1; off < 256; off <<= 1) {
            uint u = (t >= off) ? s[t - off] : 0u;
            __syncthreads();
            s[t] += u;
            __syncthreads();
        }
        if (t < BK) B[t] = s[t] - v;
        if (t == 0) { B[BK] = (uint)E; row[N] = E; }
    }
}

// ---------------- K3: scatter edges into bucket regions (LDS cursors) ----------------
__global__ void scatter_kernel(const int* __restrict__ src, const int* __restrict__ dst,
                               const uint* __restrict__ H, const uint* __restrict__ B,
                               uint* __restrict__ EB, int E, int CHN) {
    __shared__ uint cur[BK];
    int t = threadIdx.x, c = blockIdx.x;
    if (t < BK) cur[t] = B[t] + H[t * CHN + c];
    __syncthreads();
    int e0 = c * CHUNK;
    for (int i = t; i < CHUNK; i += 256) {
        int e = e0 + i;
        if (e < E) {
            int d = dst[e];
            uint slot = atomicAdd(&cur[d >> 8], 1u);
            EB[slot] = ((uint)(d & 255) << 16) | (uint)src[e];
        }
    }
}

// ---------------- K4: bucket_sort (blocks 0..BK-1)  ||  MFMA gemm (blocks BK..) ----------------
// Sort: per-bucket counting sort by dst&255 -> esrc, row, dinv (dense writes).
// Gemm: g16[M,128] = bf16( x @ W1 )  -- UNSCALED (dinv applied per-edge in gather),
//       so gemm has no dependence on sort outputs; safe to run concurrently.
#define WT_STRIDE 136
union SortGemmSmem {
    struct { uint cnt[256], s[256], cur[256]; } sort;
    u16 wt[128 * WT_STRIDE];               // 34.8 KB
};
__global__ __launch_bounds__(256) void sortgemm_kernel(
    const uint* __restrict__ EB, const uint* __restrict__ B,
    int* __restrict__ row, float* __restrict__ dinv, u16* __restrict__ esrc,
    const float* __restrict__ A, const float* __restrict__ W,
    uint* __restrict__ G32, int N, int M) {
    __shared__ SortGemmSmem sm;
    int t = threadIdx.x;

    if (blockIdx.x < BK) {                 // ---- bucket sort ----
        int b = blockIdx.x;
        uint base = B[b], ne = B[b + 1] - base;
        sm.sort.cnt[t] = 0;
        __syncthreads();
        for (uint i = t; i < ne; i += 256) atomicAdd(&sm.sort.cnt[EB[base + i] >> 16], 1u);
        __syncthreads();
        uint c = sm.sort.cnt[t];
        sm.sort.s[t] = c;
        __syncthreads();
#pragma unroll
        for (int off = 1; off < 256; off <<= 1) {
            uint u = (t >= off) ? sm.sort.s[t - off] : 0u;
            __syncthreads();
            sm.sort.s[t] += u;
            __syncthreads();
        }
        uint p = sm.sort.s[t] - c;          // exclusive prefix within bucket
        int v = (b << 8) + t;
        if (v < N) {
            row[v] = (int)(base + p);
            dinv[v] = rsqrtf((float)(c + 1u));   // +1 self-loop
        }
        sm.sort.cur[t] = base + p;
        __syncthreads();
        for (uint i = t; i < ne; i += 256) {
            uint u = EB[base + i];
            uint slot = atomicAdd(&sm.sort.cur[u >> 16], 1u);
            esrc[slot] = (u16)(u & 0xffffu);
        }
    } else {                               // ---- MFMA gemm ----
        int bid = blockIdx.x - BK;
        for (int i = t; i < 128 * 128; i += 256) {   // stage W1^T as bf16
            int k = i >> 7, n = i & 127;
            sm.wt[n * WT_STRIDE + k] = cvt_bf16(W[i]);
        }
        __syncthreads();

        int wave = t >> 6, lane = t & 63;
        int m = lane & 15, quad = lane >> 4;
        int rowa = bid * 64 + wave * 16 + m;
        int rowc = rowa < M ? rowa : M - 1;
        const float* Arow = A + (long)rowc * D;

        short8 afrag[4];
#pragma unroll
        for (int kt = 0; kt < 4; kt++) {
            int k0 = kt * 32 + quad * 8;
            float4 f0 = *(const float4*)(Arow + k0);
            float4 f1 = *(const float4*)(Arow + k0 + 4);
            short8 af;
            af[0] = (short)cvt_bf16(f0.x); af[1] = (short)cvt_bf16(f0.y);
            af[2] = (short)cvt_bf16(f0.z); af[3] = (short)cvt_bf16(f0.w);
            af[4] = (short)cvt_bf16(f1.x); af[5] = (short)cvt_bf16(f1.y);
            af[6] = (short)cvt_bf16(f1.z); af[7] = (short)cvt_bf16(f1.w);
            afrag[kt] = af;
        }

        int orow0 = bid * 64 + wave * 16;
        for (int n0 = 0; n0 < 128; n0 += 16) {
            floatx4 acc = {0.f, 0.f, 0.f, 0.f};
#pragma unroll
            for (int kt = 0; kt < 4; kt++) {
                short8 bf = *(const short8*)(sm.wt + (n0 + m) * WT_STRIDE + kt * 32 + quad * 8);
                acc = __builtin_amdgcn_mfma_f32_16x16x32_bf16(afrag[kt], bf, acc, 0, 0, 0);
            }
#pragma unroll
            for (int r = 0; r < 4; r++) {
                float val = acc[r];
                float oth = __shfl_xor(val, 1, 64);      // partner column
                int orow = orow0 + quad * 4 + r;
                if (orow < M && (m & 1) == 0)
                    G32[(long)orow * 64 + ((n0 + m) >> 1)] = pack_bf2(val, oth);
            }
        }
    }
}

// ---------------- K5: fused gather(bf16, dinv-fma) + leakyrelu + dot(w2m) ----------------
// One wave/node; 8 chains x 8 lanes. R12: 4-edge flat batch per chain-iter,
// all loads (4 esrc -> 4 dinv + 8 gv) issued before ACCs; tail by clamp+w=0.
__global__ __launch_bounds__(256) void gather_node_kernel(
    const int* __restrict__ row, const u16* __restrict__ esrc,
    const uint* __restrict__ g16, const float* __restrict__ dinv,
    const float* __restrict__ b1, const float* __restrict__ w2m,
    float* __restrict__ mg, int N) {
    int wave = threadIdx.x >> 6;
    int lane = threadIdx.x & 63;
    int sub = lane & 7;        // 16-channel slice: uint4 pair 2*sub, 2*sub+1
    int nb = lane >> 3;        // 8 neighbor chains
    int v = blockIdx.x * 4 + wave;
    if (v >= N) return;

    const uint4* gv = (const uint4*)g16;   // 16 uint4 per 256B row
    float dvv = dinv[v];
    float acc[16];
#pragma unroll
    for (int i = 0; i < 16; i++) acc[i] = 0.f;

#define ACC8(ua, ub, wgt) {                                              \
    uint uu[8] = {(ua).x, (ua).y, (ua).z, (ua).w, (ub).x, (ub).y, (ub).z, (ub).w}; \
    _Pragma("unroll")                                                    \
    for (int i = 0; i < 8; i++) {                                        \
        acc[2*i]   += (wgt) * __uint_as_float(uu[i] << 16);              \
        acc[2*i+1] += (wgt) * __uint_as_float(uu[i] & 0xffff0000u);      \
    } }

    if (nb == 0) {             // self-loop term: dinv[v]*h[v]
        int rb = v * 16 + 2 * sub;
        uint4 ua = gv[rb], ub = gv[rb + 1];
        ACC8(ua, ub, dvv)
    }
    int jb = row[v], je = row[v + 1];
    int j = jb + nb;
    while (j < je) {           // 4-edge batch; OOB slots clamp to j and get w=0
        int j1 = j + 8, j2 = j + 16, j3 = j + 24;
        int s0 = esrc[j];
        int s1 = esrc[j1 < je ? j1 : j];
        int s2 = esrc[j2 < je ? j2 : j];
        int s3 = esrc[j3 < je ? j3 : j];
        float w0 = dinv[s0];
        float w1 = (j1 < je) ? dinv[s1] : 0.f;
        float w2 = (j2 < je) ? dinv[s2] : 0.f;
        float w3 = (j3 < je) ? dinv[s3] : 0.f;
        int r0 = s0 * 16 + 2 * sub;
        int r1 = s1 * 16 + 2 * sub;
        int r2 = s2 * 16 + 2 * sub;
        int r3 = s3 * 16 + 2 * sub;
        uint4 a0 = gv[r0], a1 = gv[r0 + 1];
        uint4 b0 = gv[r1], b1v = gv[r1 + 1];
        uint4 c0 = gv[r2], c1 = gv[r2 + 1];
        uint4 d0 = gv[r3], d1 = gv[r3 + 1];
        j += 32;
        ACC8(a0, a1, w0)
        ACC8(b0, b1v, w1)
        ACC8(c0, c1, w2)
        ACC8(d0, d1, w3)
    }
#undef ACC8

    // reduce the 8 chains
#pragma unroll
    for (int i = 0; i < 16; i++) {
        acc[i] += __shfl_xor(acc[i], 8, 64);
        acc[i] += __shfl_xor(acc[i], 16, 64);
        acc[i] += __shfl_xor(acc[i], 32, 64);
    }

    if (nb == 0) {             // lane sub holds channels 16*sub .. 16*sub+15
        const float4* bp = (const float4*)b1;
        const float4* wp = (const float4*)w2m;
        float s = 0.f;
#pragma unroll
        for (int q4 = 0; q4 < 4; q4++) {
            float4 bb = bp[sub * 4 + q4];
            float4 wm = wp[sub * 4 + q4];
            float t0 = dvv * acc[4*q4 + 0] + bb.x; t0 = t0 >= 0.f ? t0 : 0.1f * t0;
            float t1 = dvv * acc[4*q4 + 1] + bb.y; t1 = t1 >= 0.f ? t1 : 0.1f * t1;
            float t2 = dvv * acc[4*q4 + 2] + bb.z; t2 = t2 >= 0.f ? t2 : 0.1f * t2;
            float t3 = dvv * acc[4*q4 + 3] + bb.w; t3 = t3 >= 0.f ? t3 : 0.1f * t3;
            s += t0 * wm.x + t1 * wm.y + t2 * wm.z + t3 * wm.w;
        }
        s += __shfl_xor(s, 1, 64);
        s += __shfl_xor(s, 2, 64);
        s += __shfl_xor(s, 4, 64);
        if (sub == 0) mg[v] = dvv * s;
    }
}

// ---------------- K6: scalar aggregate for conv2 + mean ----------------
__global__ void out_kernel(const int* __restrict__ row, const u16* __restrict__ esrc,
                           const float* __restrict__ mg, const float* __restrict__ dinv,
                           const float* __restrict__ w2m, float* __restrict__ out, int N) {
    int v = blockIdx.x * blockDim.x + threadIdx.x;
    if (v >= N) return;
    float acc = mg[v];
    int jb = row[v], je = row[v + 1];
    int j = jb;
    for (; j + 8 <= je; j += 8) {
        acc += mg[esrc[j]] + mg[esrc[j + 1]] + mg[esrc[j + 2]] + mg[esrc[j + 3]] +
               mg[esrc[j + 4]] + mg[esrc[j + 5]] + mg[esrc[j + 6]] + mg[esrc[j + 7]];
    }
    for (; j < je; j++) acc += mg[esrc[j]];
    out[v] = dinv[v] * acc + w2m[128];
}

extern "C" void kernel_launch(void* const* d_in, const int* in_sizes, int n_in,
                              void* d_out, int out_size, void* d_ws, size_t ws_size,
                              hipStream_t stream) {
    const float* x  = (const float*)d_in[0];
    const int* ei   = (const int*)d_in[1];
    const float* W1 = (const float*)d_in[2];
    const float* b1 = (const float*)d_in[3];
    const float* W2 = (const float*)d_in[4];
    const float* b2 = (const float*)d_in[5];
    float* out = (float*)d_out;

    const int N = N_NODES;
    const int E = in_sizes[1] / 2;
    const int* src = ei;
    const int* dst = ei + E;
    const int CHN = (E + CHUNK - 1) / CHUNK;   // 391
    const int nblocks = (N + 255) / 256;       // 196

    // workspace (4B units). EB is NOT aliased with g16 (sort runs || gemm in K4).
    float*    dinv    = (float*)d_ws;                     // [NPAD]
    int*      row     = (int*)(dinv + NPAD);              // [NPAD+16]
    uint*     B       = (uint*)(row + NPAD + 16);         // [256] (BK+1 used)
    float*    w2m     = (float*)(B + 256);                // [256] ([128]=mean b2)
    float*    mg      = w2m + 256;                        // [NPAD]
    uint*     T       = (uint*)(mg + NPAD);               // [256]
    uint*     counter = T + 256;                          // [16]
    uint*     g16u    = counter + 16;                     // [NPAD*64] (16B aligned)
    u16*      esrc    = (u16*)(g16u + (long)NPAD * 64);   // [E] u16
    uint*     H       = (uint*)(esrc + E);                // [BK*CHN]
    uint*     EB      = H + BK * CHN;                     // [E]

    // K1: histogram chunks + w2m + counter init
    hist_w2m_kernel<<<CHN + 1, 256, 0, stream>>>(dst, H, W2, b2, w2m, counter, E, CHN);
    // K2: per-bucket chunk scan; last block produces B[] and row[N]
    scan_kernel<<<BK, 256, 0, stream>>>(H, T, B, row, counter, CHN, E, N);
    // K3: scatter into bucket regions
    scatter_kernel<<<CHN, 256, 0, stream>>>(src, dst, H, B, EB, E, CHN);
    // K4: bucket sort (196 blocks) || MFMA gemm (782 blocks)
    sortgemm_kernel<<<BK + (N + 63) / 64, 256, 0, stream>>>(EB, B, row, dinv, esrc,
                                                            x, W1, g16u, N, N);
    // K5: gather + lrelu + dot -> mg
    gather_node_kernel<<<(N + 3) / 4, 256, 0, stream>>>(row, esrc, g16u, dinv, b1, w2m, mg, N);
    // K6: scalar aggregate + mean -> out
    out_kernel<<<nblocks, 256, 0, stream>>>(row, esrc, mg, dinv, w2m, out, N);
}